// Round 18
// baseline (220.690 us; speedup 1.0000x reference)
//
#include <hip/hip_runtime.h>

#define TH  0.3f
#define DEC 0.2f

// LDS layout (float offsets) — X stride 42, S stride 26 (anti-bank-conflict)
#define OFF_X    0        // 38 rows x 42 = 1596 (x, zero-padded border, cols 38..41 unused)
#define OFF_W1   1596     // 10*28 = 280  (repack: [oc][k*9+j], pad to 28)
#define OFF_B1   1876     // 30 (pad 32)
#define OFF_W2   1908     // 100*28 = 2800 (repack: [oc][ic][k*9+j], pad 28)
#define OFF_B2   4708     // 30 (pad 32)
#define OFF_LIF  4740     // 4
#define OFF_S    4744     // 10 oc x 20 rows x 26 = 5200 (pooled L1 spikes); h1 in epilogue
#define OFF_C1X  9944     // 168 overflow L1 cells x 17-float stride
#define OFF_C2   12800    // 810 L2 cells x 17-float stride
#define SMEM_N   26570    // 106,280 bytes

__device__ __forceinline__ float spikef(float v) { return v > TH ? 1.f : 0.f; }

// ---- AGPR residency: "=a"/"a" constraints pin values into the accum half
// of the unified register file (otherwise unused: no MFMA in this kernel).
__device__ __forceinline__ float ag_w(float v) {
    float a;
    asm("v_accvgpr_write_b32 %0, %1" : "=a"(a) : "v"(v));
    return a;
}
__device__ __forceinline__ float ag_r(float a) {
    float v;
    asm("v_accvgpr_read_b32 %0, %1" : "=v"(v) : "a"(a));
    return v;
}

#define AG16_DECL(P) \
    float P##0=ag_w(0.f), P##1=ag_w(0.f), P##2=ag_w(0.f), P##3=ag_w(0.f),   \
          P##4=ag_w(0.f), P##5=ag_w(0.f), P##6=ag_w(0.f), P##7=ag_w(0.f),   \
          P##8=ag_w(0.f), P##9=ag_w(0.f), P##10=ag_w(0.f), P##11=ag_w(0.f), \
          P##12=ag_w(0.f), P##13=ag_w(0.f), P##14=ag_w(0.f), P##15=ag_w(0.f)

// LIF update of one float4 state M (k0..k2 in x,y,z; hh-channel in w), drives D0..D2.
// inner_ computed from OLD mem (reference order).
#define LIF4(M, D0, D1, D2)                                            \
    {                                                                  \
        float inner_ = fmaf((M).x, lw0, fmaf((M).y, lw1, fmaf((M).z, lw2, lb))); \
        (M).x = ((M).x > TH ? 0.f : (M).x * DEC) + (D0);               \
        (M).y = ((M).y > TH ? 0.f : (M).y * DEC) + (D1);               \
        (M).z = ((M).z > TH ? 0.f : (M).z * DEC) + (D2);               \
        (M).w = ((M).w > TH ? 0.f : (M).w * DEC) + inner_;             \
    }

// stream 27 weights (float4 chunks, immediate consumption), ACC(k,r,c,w)
#define CONV27(WB, ACC)                                                      \
    do {                                                                     \
        float4 w4_;                                                          \
        _Pragma("unroll")                                                    \
        for (int j_ = 0; j_ < 27; ++j_) {                                    \
            if ((j_ & 3) == 0)                                               \
                w4_ = *reinterpret_cast<const float4*>(&sm[(WB) + j_]);      \
            const float wv_ = ((j_ & 3) == 0) ? w4_.x :                      \
                              ((j_ & 3) == 1) ? w4_.y :                      \
                              ((j_ & 3) == 2) ? w4_.z : w4_.w;               \
            const int k_ = j_ / 9, r_ = (j_ - k_ * 9) / 3,                   \
                      c_ = j_ - k_ * 9 - r_ * 3;                             \
            ACC(k_, r_, c_, wv_);                                            \
        }                                                                    \
    } while (0)

#define ACC_L1(K, R, C, W)                                   \
    d[0][K] = fmaf(xv[R][C],         (W), d[0][K]);          \
    d[1][K] = fmaf(xv[R][C + 1],     (W), d[1][K]);          \
    d[2][K] = fmaf(xv[R + 1][C],     (W), d[2][K]);          \
    d[3][K] = fmaf(xv[R + 1][C + 1], (W), d[3][K]);

#define ACC_L2(K, R, C, W)                                   \
    acc[0][K] = fmaf(sv[R][C],         (W), acc[0][K]);      \
    acc[1][K] = fmaf(sv[R][C + 1],     (W), acc[1][K]);      \
    acc[2][K] = fmaf(sv[R + 1][C],     (W), acc[2][K]);      \
    acc[3][K] = fmaf(sv[R + 1][C + 1], (W), acc[3][K]);

// ---- layer-1 conv drives only (no state touched) ----
__device__ __forceinline__ void conv1(const float* __restrict__ sm, int cell,
                                      float (&d)[4][3])
{
    int oc  = cell / 324;
    int rem = cell - oc * 324;
    int hh  = rem / 18;
    int ww  = rem - hh * 18;
    int y0 = 2 * hh, x0 = 2 * ww;

    float xv[4][4];
#pragma unroll
    for (int r = 0; r < 4; ++r) {
        float2 a = *reinterpret_cast<const float2*>(&sm[OFF_X + (y0 + r) * 42 + x0]);
        float2 b = *reinterpret_cast<const float2*>(&sm[OFF_X + (y0 + r) * 42 + x0 + 2]);
        xv[r][0] = a.x; xv[r][1] = a.y; xv[r][2] = b.x; xv[r][3] = b.y;
    }
    {
        float b0  = sm[OFF_B1 + oc];
        float b1v = sm[OFF_B1 + 10 + oc];
        float b2v = sm[OFF_B1 + 20 + oc];
#pragma unroll
        for (int p = 0; p < 4; ++p) { d[p][0] = b0; d[p][1] = b1v; d[p][2] = b2v; }
    }
    CONV27(OFF_W1 + oc * 28, ACC_L1);
}

// sv window load for one input channel (4x4 block of S)
__device__ __forceinline__ void sv_load(const float* __restrict__ sm, int sb, int ic,
                                        float (&sv)[4][4])
{
#pragma unroll
    for (int r = 0; r < 4; ++r) {
        float2 a = *reinterpret_cast<const float2*>(&sm[sb + ic * 520 + r * 26]);
        float2 b = *reinterpret_cast<const float2*>(&sm[sb + ic * 520 + r * 26 + 2]);
        sv[r][0] = a.x; sv[r][1] = a.y; sv[r][2] = b.x; sv[r][3] = b.y;
    }
}

// ---- layer-2 conv drives only — ic loop manually software-pipelined 2-deep:
// prefetch sv(ic+1) while FMA-ing sv(ic). Named buffers svA/svB, fully
// unrolled -> static indexing (no scratch). Accumulation order (ic ascending)
// unchanged -> bit-identical results.
__device__ __forceinline__ void conv2(const float* __restrict__ sm, int cell,
                                      float (&acc)[4][3])
{
    int oc  = cell / 81;
    int rem = cell - oc * 81;
    int hh  = rem / 9;
    int ww  = rem - hh * 9;
    int y0 = 2 * hh, x0 = 2 * ww;

    {
        float b20 = 4.f * sm[OFF_B2 + oc];
        float b21 = 4.f * sm[OFF_B2 + 10 + oc];
        float b22 = 4.f * sm[OFF_B2 + 20 + oc];
#pragma unroll
        for (int p = 0; p < 4; ++p) { acc[p][0] = b20; acc[p][1] = b21; acc[p][2] = b22; }
    }

    const int sb = OFF_S + y0 * 26 + x0;
    const int wb = OFF_W2 + (oc * 10) * 28;

    float svA[4][4], svB[4][4];
    sv_load(sm, sb, 0, svA);
#pragma unroll
    for (int icp = 0; icp < 5; ++icp) {
        const int ic0 = 2 * icp, ic1 = ic0 + 1;
        sv_load(sm, sb, ic1, svB);            // prefetch odd ic under even-ic FMAs
        {
            float (&sv)[4][4] = svA;
            CONV27(wb + ic0 * 28, ACC_L2);
        }
        if (icp < 4)
            sv_load(sm, sb, ic1 + 1, svA);    // prefetch next even ic under odd-ic FMAs
        {
            float (&sv)[4][4] = svB;
            CONV27(wb + ic1 * 28, ACC_L2);
        }
    }
}

// one AGPR-resident L1 cell: conv first, then per-pixel LIF (only 4 state
// floats live in VGPRs at a time)
#define L1_AG_CELL(P, CELL)                                                   \
    {                                                                         \
        const int cell_ = (CELL);                                             \
        float d[4][3];                                                        \
        conv1(sm, cell_, d);                                                  \
        float ssum = 0.f; float4 m;                                           \
        m = make_float4(ag_r(P##0), ag_r(P##1), ag_r(P##2), ag_r(P##3));      \
        LIF4(m, d[0][0], d[0][1], d[0][2]);                                   \
        ssum += spikef(m.x) + spikef(m.y) + spikef(m.z) + spikef(m.w);        \
        P##0=ag_w(m.x); P##1=ag_w(m.y); P##2=ag_w(m.z); P##3=ag_w(m.w);       \
        m = make_float4(ag_r(P##4), ag_r(P##5), ag_r(P##6), ag_r(P##7));      \
        LIF4(m, d[1][0], d[1][1], d[1][2]);                                   \
        ssum += spikef(m.x) + spikef(m.y) + spikef(m.z) + spikef(m.w);        \
        P##4=ag_w(m.x); P##5=ag_w(m.y); P##6=ag_w(m.z); P##7=ag_w(m.w);       \
        m = make_float4(ag_r(P##8), ag_r(P##9), ag_r(P##10), ag_r(P##11));    \
        LIF4(m, d[2][0], d[2][1], d[2][2]);                                   \
        ssum += spikef(m.x) + spikef(m.y) + spikef(m.z) + spikef(m.w);        \
        P##8=ag_w(m.x); P##9=ag_w(m.y); P##10=ag_w(m.z); P##11=ag_w(m.w);     \
        m = make_float4(ag_r(P##12), ag_r(P##13), ag_r(P##14), ag_r(P##15));  \
        LIF4(m, d[3][0], d[3][1], d[3][2]);                                   \
        ssum += spikef(m.x) + spikef(m.y) + spikef(m.z) + spikef(m.w);        \
        P##12=ag_w(m.x); P##13=ag_w(m.y); P##14=ag_w(m.z); P##15=ag_w(m.w);   \
        int oc_ = cell_ / 324, rem_ = cell_ - oc_ * 324;                      \
        int hh_ = rem_ / 18, ww_ = rem_ - hh_ * 18;                           \
        sm[OFF_S + oc_ * 520 + (hh_ + 1) * 26 + (ww_ + 1)] = ssum * 0.25f;    \
    }

__attribute__((amdgpu_waves_per_eu(4, 4)))
__global__ __launch_bounds__(1024)
void scnn_kernel(const float* __restrict__ x,
                 const float* __restrict__ w1, const float* __restrict__ b1,
                 const float* __restrict__ w2, const float* __restrict__ b2,
                 const float* __restrict__ lif_w, const float* __restrict__ lif_b,
                 const float* __restrict__ fc_w, const float* __restrict__ fc_b,
                 const float* __restrict__ task_w, const float* __restrict__ task_b,
                 const int* __restrict__ tw_ptr,
                 float* __restrict__ out)
{
    __shared__ float sm[SMEM_N];
    const int tid = threadIdx.x;
    const int b   = blockIdx.x;
    const int T   = tw_ptr[0];

    for (int i = tid; i < SMEM_N; i += 1024) sm[i] = 0.f;
    __syncthreads();

    for (int i = tid; i < 1296; i += 1024) {
        int h = i / 36, w = i - h * 36;
        sm[OFF_X + (h + 1) * 42 + (w + 1)] = x[b * 1296 + i];
    }
    if (tid < 270) { // w1 (3,10,1,3,3) -> [oc][k*9+j] pad 28
        int k = tid / 90, r = tid - k * 90;
        int oc = r / 9, j = r - oc * 9;
        sm[OFF_W1 + oc * 28 + k * 9 + j] = w1[tid];
    }
    if (tid < 30)  sm[OFF_B1 + tid] = b1[tid];
    for (int i = tid; i < 2700; i += 1024) { // w2 (3,10,10,3,3) -> [oc][ic][k*9+j] pad 28
        int k = i / 900, r1 = i - k * 900;
        int oc = r1 / 90, r2 = r1 - oc * 90;
        int ic = r2 / 9,  j  = r2 - ic * 9;
        sm[OFF_W2 + (oc * 10 + ic) * 28 + k * 9 + j] = w2[i];
    }
    if (tid < 30)  sm[OFF_B2 + tid] = b2[tid];
    if (tid < 3)   sm[OFF_LIF + tid] = lif_w[tid];
    if (tid == 0)  sm[OFF_LIF + 3] = lif_b[0];
    __syncthreads();

    const float lw0 = sm[OFF_LIF + 0], lw1 = sm[OFF_LIF + 1],
                lw2 = sm[OFF_LIF + 2], lb  = sm[OFF_LIF + 3];

    // persistent AGPR state: 48 floats (3 L1 cells). L2 + overflow state in LDS.
    AG16_DECL(aA);   // L1 cell tid
    AG16_DECL(aB);   // L1 cell tid+1024
    AG16_DECL(aC);   // L1 cell tid+2048
    float hA0=0.f,hA1=0.f,hA2=0.f,hA3=0.f;   // h1 accumulators (VGPR)

    for (int t = 0; t < T; ++t) {
        // no sched_barrier fences (R17 win): scheduler pipelines ds_read latency
        // of cell N+1 under the FMA tail of cell N
        L1_AG_CELL(aA, tid);
        L1_AG_CELL(aB, tid + 1024);
        L1_AG_CELL(aC, tid + 2048);
        if (tid < 3240 - 3072) {   // 168 overflow cells: LDS state, odd stride
            const int cell = tid + 3072;
            float d[4][3];
            conv1(sm, cell, d);
            float* cp = &sm[OFF_C1X + tid * 17];
            float ssum = 0.f;
#pragma unroll
            for (int p = 0; p < 4; ++p) {
                float4 m = make_float4(cp[4*p], cp[4*p+1], cp[4*p+2], cp[4*p+3]);
                LIF4(m, d[p][0], d[p][1], d[p][2]);
                ssum += spikef(m.x) + spikef(m.y) + spikef(m.z) + spikef(m.w);
                cp[4*p] = m.x; cp[4*p+1] = m.y; cp[4*p+2] = m.z; cp[4*p+3] = m.w;
            }
            int oc_ = cell / 324, rem_ = cell - oc_ * 324;
            int hh_ = rem_ / 18, ww_ = rem_ - hh_ * 18;
            sm[OFF_S + oc_ * 520 + (hh_ + 1) * 26 + (ww_ + 1)] = ssum * 0.25f;
        }
        __syncthreads();

        if (tid < 810) {           // L2: conv from S (sw-pipelined), state in LDS
            float acc[4][3];
            conv2(sm, tid, acc);
            float* cp = &sm[OFF_C2 + tid * 17];
#pragma unroll
            for (int p = 0; p < 4; ++p) {
                float4 m = make_float4(cp[4*p], cp[4*p+1], cp[4*p+2], cp[4*p+3]);
                LIF4(m, acc[p][0], acc[p][1], acc[p][2]);
                hA0 += spikef(m.x) * 0.25f; hA1 += spikef(m.y) * 0.25f;
                hA2 += spikef(m.z) * 0.25f; hA3 += spikef(m.w) * 0.25f;
                cp[4*p] = m.x; cp[4*p+1] = m.y; cp[4*p+2] = m.z; cp[4*p+3] = m.w;
            }
        }
        __syncthreads();
    }

    // ---- epilogue: h1 -> S region, FC(50x3240), task heads ----
    if (tid < 810)
        *reinterpret_cast<float4*>(&sm[OFF_S + tid * 4]) = make_float4(hA0, hA1, hA2, hA3);
    __syncthreads();

    float invT = 1.f / (float)T;
    int f = tid >> 4, g = tid & 15;
    if (f < 50) {
        const float* wrow = fc_w + f * 3240;
        float p0 = 0.f, p1 = 0.f;
        for (int j = g; j + 16 < 3240; j += 32) {
            p0 = fmaf(sm[OFF_S + j], wrow[j], p0);
            p1 = fmaf(sm[OFF_S + j + 16], wrow[j + 16], p1);
        }
        { int j = 3232 + g; if (j < 3240) p0 = fmaf(sm[OFF_S + j], wrow[j], p0); }
        float p = p0 + p1;
        p += __shfl_xor(p, 1);
        p += __shfl_xor(p, 2);
        p += __shfl_xor(p, 4);
        p += __shfl_xor(p, 8);
        if (g == 0) sm[OFF_X + f] = p * invT + fc_b[f];
    }
    __syncthreads();

    if (tid < 30) {
        float acc = task_b[tid];
        const float* twp = task_w + tid * 50;
        for (int j = 0; j < 50; ++j) acc = fmaf(sm[OFF_X + j], twp[j], acc);
        out[b * 30 + tid] = acc;
    }
}

extern "C" void kernel_launch(void* const* d_in, const int* in_sizes, int n_in,
                              void* d_out, int out_size, void* d_ws, size_t ws_size,
                              hipStream_t stream) {
    const float* x      = (const float*)d_in[0];
    const float* w1     = (const float*)d_in[1];
    const float* b1     = (const float*)d_in[2];
    const float* w2     = (const float*)d_in[3];
    const float* b2     = (const float*)d_in[4];
    const float* lif_w  = (const float*)d_in[5];
    const float* lif_b  = (const float*)d_in[6];
    const float* fc_w   = (const float*)d_in[7];
    const float* fc_b   = (const float*)d_in[8];
    const float* task_w = (const float*)d_in[9];
    const float* task_b = (const float*)d_in[10];
    const int*   tw     = (const int*)d_in[11];

    int B = in_sizes[0] / 1296;  // x is (B,1,36,36)

    scnn_kernel<<<B, 1024, 0, stream>>>(x, w1, b1, w2, b2, lif_w, lif_b,
                                        fc_w, fc_b, task_w, task_b, tw,
                                        (float*)d_out);
}

// Round 19
// 199.651 us; speedup vs baseline: 1.1054x; 1.1054x over previous
//
#include <hip/hip_runtime.h>

#define TH  0.3f
#define DEC 0.2f

// LDS layout (float offsets) — X stride 42, S stride 26 (anti-bank-conflict)
#define OFF_X    0        // 38 rows x 42 = 1596 (x, zero-padded border, cols 38..41 unused)
#define OFF_W1   1596     // 10*28 = 280  (repack: [oc][k*9+j], pad to 28)
#define OFF_B1   1876     // 30 (pad 32)
#define OFF_W2   1908     // 100*28 = 2800 (repack: [oc][ic][k*9+j], pad 28)
#define OFF_B2   4708     // 30 (pad 32)
#define OFF_LIF  4740     // 4
#define OFF_S    4744     // 10 oc x 20 rows x 26 = 5200 (pooled L1 spikes); h1 in epilogue
#define OFF_C1X  9944     // 168 overflow L1 cells x 17-float stride
#define OFF_C2   12800    // 810 L2 cells x 17-float stride
#define SMEM_N   26570    // 106,280 bytes

__device__ __forceinline__ float spikef(float v) { return v > TH ? 1.f : 0.f; }

// ---- AGPR residency: "=a"/"a" constraints pin values into the accum half
// of the unified register file (otherwise unused: no MFMA in this kernel).
__device__ __forceinline__ float ag_w(float v) {
    float a;
    asm("v_accvgpr_write_b32 %0, %1" : "=a"(a) : "v"(v));
    return a;
}
__device__ __forceinline__ float ag_r(float a) {
    float v;
    asm("v_accvgpr_read_b32 %0, %1" : "=v"(v) : "a"(a));
    return v;
}

#define AG16_DECL(P) \
    float P##0=ag_w(0.f), P##1=ag_w(0.f), P##2=ag_w(0.f), P##3=ag_w(0.f),   \
          P##4=ag_w(0.f), P##5=ag_w(0.f), P##6=ag_w(0.f), P##7=ag_w(0.f),   \
          P##8=ag_w(0.f), P##9=ag_w(0.f), P##10=ag_w(0.f), P##11=ag_w(0.f), \
          P##12=ag_w(0.f), P##13=ag_w(0.f), P##14=ag_w(0.f), P##15=ag_w(0.f)

// LIF update of one float4 state M (k0..k2 in x,y,z; hh-channel in w), drives D0..D2.
// inner_ computed from OLD mem (reference order).
#define LIF4(M, D0, D1, D2)                                            \
    {                                                                  \
        float inner_ = fmaf((M).x, lw0, fmaf((M).y, lw1, fmaf((M).z, lw2, lb))); \
        (M).x = ((M).x > TH ? 0.f : (M).x * DEC) + (D0);               \
        (M).y = ((M).y > TH ? 0.f : (M).y * DEC) + (D1);               \
        (M).z = ((M).z > TH ? 0.f : (M).z * DEC) + (D2);               \
        (M).w = ((M).w > TH ? 0.f : (M).w * DEC) + inner_;             \
    }

// stream 27 weights (float4 chunks, immediate consumption), ACC(k,r,c,w)
#define CONV27(WB, ACC)                                                      \
    do {                                                                     \
        float4 w4_;                                                          \
        _Pragma("unroll")                                                    \
        for (int j_ = 0; j_ < 27; ++j_) {                                    \
            if ((j_ & 3) == 0)                                               \
                w4_ = *reinterpret_cast<const float4*>(&sm[(WB) + j_]);      \
            const float wv_ = ((j_ & 3) == 0) ? w4_.x :                      \
                              ((j_ & 3) == 1) ? w4_.y :                      \
                              ((j_ & 3) == 2) ? w4_.z : w4_.w;               \
            const int k_ = j_ / 9, r_ = (j_ - k_ * 9) / 3,                   \
                      c_ = j_ - k_ * 9 - r_ * 3;                             \
            ACC(k_, r_, c_, wv_);                                            \
        }                                                                    \
    } while (0)

#define ACC_L1(K, R, C, W)                                   \
    d[0][K] = fmaf(xv[R][C],         (W), d[0][K]);          \
    d[1][K] = fmaf(xv[R][C + 1],     (W), d[1][K]);          \
    d[2][K] = fmaf(xv[R + 1][C],     (W), d[2][K]);          \
    d[3][K] = fmaf(xv[R + 1][C + 1], (W), d[3][K]);

#define ACC_L2(K, R, C, W)                                   \
    acc[0][K] = fmaf(sv[R][C],         (W), acc[0][K]);      \
    acc[1][K] = fmaf(sv[R][C + 1],     (W), acc[1][K]);      \
    acc[2][K] = fmaf(sv[R + 1][C],     (W), acc[2][K]);      \
    acc[3][K] = fmaf(sv[R + 1][C + 1], (W), acc[3][K]);

// ---- layer-1 conv drives only (no state touched) ----
__device__ __forceinline__ void conv1(const float* __restrict__ sm, int cell,
                                      float (&d)[4][3])
{
    int oc  = cell / 324;
    int rem = cell - oc * 324;
    int hh  = rem / 18;
    int ww  = rem - hh * 18;
    int y0 = 2 * hh, x0 = 2 * ww;

    float xv[4][4];
#pragma unroll
    for (int r = 0; r < 4; ++r) {
        float2 a = *reinterpret_cast<const float2*>(&sm[OFF_X + (y0 + r) * 42 + x0]);
        float2 b = *reinterpret_cast<const float2*>(&sm[OFF_X + (y0 + r) * 42 + x0 + 2]);
        xv[r][0] = a.x; xv[r][1] = a.y; xv[r][2] = b.x; xv[r][3] = b.y;
    }
    {
        float b0  = sm[OFF_B1 + oc];
        float b1v = sm[OFF_B1 + 10 + oc];
        float b2v = sm[OFF_B1 + 20 + oc];
#pragma unroll
        for (int p = 0; p < 4; ++p) { d[p][0] = b0; d[p][1] = b1v; d[p][2] = b2v; }
    }
    CONV27(OFF_W1 + oc * 28, ACC_L1);
}

// ---- layer-2 conv drives only ----
__device__ __forceinline__ void conv2(const float* __restrict__ sm, int cell,
                                      float (&acc)[4][3])
{
    int oc  = cell / 81;
    int rem = cell - oc * 81;
    int hh  = rem / 9;
    int ww  = rem - hh * 9;
    int y0 = 2 * hh, x0 = 2 * ww;

    {
        float b20 = 4.f * sm[OFF_B2 + oc];
        float b21 = 4.f * sm[OFF_B2 + 10 + oc];
        float b22 = 4.f * sm[OFF_B2 + 20 + oc];
#pragma unroll
        for (int p = 0; p < 4; ++p) { acc[p][0] = b20; acc[p][1] = b21; acc[p][2] = b22; }
    }

    const int sb = OFF_S + y0 * 26 + x0;
    const int wb = OFF_W2 + (oc * 10) * 28;

    for (int ic = 0; ic < 10; ++ic) {
        float sv[4][4];
#pragma unroll
        for (int r = 0; r < 4; ++r) {
            float2 a = *reinterpret_cast<const float2*>(&sm[sb + ic * 520 + r * 26]);
            float2 b = *reinterpret_cast<const float2*>(&sm[sb + ic * 520 + r * 26 + 2]);
            sv[r][0] = a.x; sv[r][1] = a.y; sv[r][2] = b.x; sv[r][3] = b.y;
        }
        CONV27(wb + ic * 28, ACC_L2);
    }
}

// one AGPR-resident L1 cell: conv first, then per-pixel LIF (only 4 state
// floats live in VGPRs at a time)
#define L1_AG_CELL(P, CELL)                                                   \
    {                                                                         \
        const int cell_ = (CELL);                                             \
        float d[4][3];                                                        \
        conv1(sm, cell_, d);                                                  \
        float ssum = 0.f; float4 m;                                           \
        m = make_float4(ag_r(P##0), ag_r(P##1), ag_r(P##2), ag_r(P##3));      \
        LIF4(m, d[0][0], d[0][1], d[0][2]);                                   \
        ssum += spikef(m.x) + spikef(m.y) + spikef(m.z) + spikef(m.w);        \
        P##0=ag_w(m.x); P##1=ag_w(m.y); P##2=ag_w(m.z); P##3=ag_w(m.w);       \
        m = make_float4(ag_r(P##4), ag_r(P##5), ag_r(P##6), ag_r(P##7));      \
        LIF4(m, d[1][0], d[1][1], d[1][2]);                                   \
        ssum += spikef(m.x) + spikef(m.y) + spikef(m.z) + spikef(m.w);        \
        P##4=ag_w(m.x); P##5=ag_w(m.y); P##6=ag_w(m.z); P##7=ag_w(m.w);       \
        m = make_float4(ag_r(P##8), ag_r(P##9), ag_r(P##10), ag_r(P##11));    \
        LIF4(m, d[2][0], d[2][1], d[2][2]);                                   \
        ssum += spikef(m.x) + spikef(m.y) + spikef(m.z) + spikef(m.w);        \
        P##8=ag_w(m.x); P##9=ag_w(m.y); P##10=ag_w(m.z); P##11=ag_w(m.w);     \
        m = make_float4(ag_r(P##12), ag_r(P##13), ag_r(P##14), ag_r(P##15));  \
        LIF4(m, d[3][0], d[3][1], d[3][2]);                                   \
        ssum += spikef(m.x) + spikef(m.y) + spikef(m.z) + spikef(m.w);        \
        P##12=ag_w(m.x); P##13=ag_w(m.y); P##14=ag_w(m.z); P##15=ag_w(m.w);   \
        int oc_ = cell_ / 324, rem_ = cell_ - oc_ * 324;                      \
        int hh_ = rem_ / 18, ww_ = rem_ - hh_ * 18;                           \
        sm[OFF_S + oc_ * 520 + (hh_ + 1) * 26 + (ww_ + 1)] = ssum * 0.25f;    \
    }

__attribute__((amdgpu_waves_per_eu(4, 4)))
__global__ __launch_bounds__(1024)
void scnn_kernel(const float* __restrict__ x,
                 const float* __restrict__ w1, const float* __restrict__ b1,
                 const float* __restrict__ w2, const float* __restrict__ b2,
                 const float* __restrict__ lif_w, const float* __restrict__ lif_b,
                 const float* __restrict__ fc_w, const float* __restrict__ fc_b,
                 const float* __restrict__ task_w, const float* __restrict__ task_b,
                 const int* __restrict__ tw_ptr,
                 float* __restrict__ out)
{
    __shared__ float sm[SMEM_N];
    const int tid = threadIdx.x;
    const int b   = blockIdx.x;
    const int T   = tw_ptr[0];

    for (int i = tid; i < SMEM_N; i += 1024) sm[i] = 0.f;
    __syncthreads();

    for (int i = tid; i < 1296; i += 1024) {
        int h = i / 36, w = i - h * 36;
        sm[OFF_X + (h + 1) * 42 + (w + 1)] = x[b * 1296 + i];
    }
    if (tid < 270) { // w1 (3,10,1,3,3) -> [oc][k*9+j] pad 28
        int k = tid / 90, r = tid - k * 90;
        int oc = r / 9, j = r - oc * 9;
        sm[OFF_W1 + oc * 28 + k * 9 + j] = w1[tid];
    }
    if (tid < 30)  sm[OFF_B1 + tid] = b1[tid];
    for (int i = tid; i < 2700; i += 1024) { // w2 (3,10,10,3,3) -> [oc][ic][k*9+j] pad 28
        int k = i / 900, r1 = i - k * 900;
        int oc = r1 / 90, r2 = r1 - oc * 90;
        int ic = r2 / 9,  j  = r2 - ic * 9;
        sm[OFF_W2 + (oc * 10 + ic) * 28 + k * 9 + j] = w2[i];
    }
    if (tid < 30)  sm[OFF_B2 + tid] = b2[tid];
    if (tid < 3)   sm[OFF_LIF + tid] = lif_w[tid];
    if (tid == 0)  sm[OFF_LIF + 3] = lif_b[0];
    __syncthreads();

    const float lw0 = sm[OFF_LIF + 0], lw1 = sm[OFF_LIF + 1],
                lw2 = sm[OFF_LIF + 2], lb  = sm[OFF_LIF + 3];

    // persistent AGPR state: 48 floats (3 L1 cells). L2 + overflow state in LDS.
    AG16_DECL(aA);   // L1 cell tid
    AG16_DECL(aB);   // L1 cell tid+1024
    AG16_DECL(aC);   // L1 cell tid+2048
    float hA0=0.f,hA1=0.f,hA2=0.f,hA3=0.f;   // h1 accumulators (VGPR)

    for (int t = 0; t < T; ++t) {
        // no sched_barrier fences (R17 win): scheduler pipelines ds_read latency
        // of cell N+1 under the FMA tail of cell N
        L1_AG_CELL(aA, tid);
        L1_AG_CELL(aB, tid + 1024);
        L1_AG_CELL(aC, tid + 2048);
        if (tid < 3240 - 3072) {   // 168 overflow cells: LDS state, odd stride
            const int cell = tid + 3072;
            float d[4][3];
            conv1(sm, cell, d);
            float* cp = &sm[OFF_C1X + tid * 17];
            float ssum = 0.f;
#pragma unroll
            for (int p = 0; p < 4; ++p) {
                float4 m = make_float4(cp[4*p], cp[4*p+1], cp[4*p+2], cp[4*p+3]);
                LIF4(m, d[p][0], d[p][1], d[p][2]);
                ssum += spikef(m.x) + spikef(m.y) + spikef(m.z) + spikef(m.w);
                cp[4*p] = m.x; cp[4*p+1] = m.y; cp[4*p+2] = m.z; cp[4*p+3] = m.w;
            }
            int oc_ = cell / 324, rem_ = cell - oc_ * 324;
            int hh_ = rem_ / 18, ww_ = rem_ - hh_ * 18;
            sm[OFF_S + oc_ * 520 + (hh_ + 1) * 26 + (ww_ + 1)] = ssum * 0.25f;
        }
        __syncthreads();

        if (tid < 810) {           // L2: conv from S, state in LDS (odd stride)
            float acc[4][3];
            conv2(sm, tid, acc);
            float* cp = &sm[OFF_C2 + tid * 17];
#pragma unroll
            for (int p = 0; p < 4; ++p) {
                float4 m = make_float4(cp[4*p], cp[4*p+1], cp[4*p+2], cp[4*p+3]);
                LIF4(m, acc[p][0], acc[p][1], acc[p][2]);
                hA0 += spikef(m.x) * 0.25f; hA1 += spikef(m.y) * 0.25f;
                hA2 += spikef(m.z) * 0.25f; hA3 += spikef(m.w) * 0.25f;
                cp[4*p] = m.x; cp[4*p+1] = m.y; cp[4*p+2] = m.z; cp[4*p+3] = m.w;
            }
        }
        __syncthreads();
    }

    // ---- epilogue: h1 -> S region, FC(50x3240), task heads ----
    if (tid < 810)
        *reinterpret_cast<float4*>(&sm[OFF_S + tid * 4]) = make_float4(hA0, hA1, hA2, hA3);
    __syncthreads();

    float invT = 1.f / (float)T;
    int f = tid >> 4, g = tid & 15;
    if (f < 50) {
        const float* wrow = fc_w + f * 3240;
        float p0 = 0.f, p1 = 0.f;
        for (int j = g; j + 16 < 3240; j += 32) {
            p0 = fmaf(sm[OFF_S + j], wrow[j], p0);
            p1 = fmaf(sm[OFF_S + j + 16], wrow[j + 16], p1);
        }
        { int j = 3232 + g; if (j < 3240) p0 = fmaf(sm[OFF_S + j], wrow[j], p0); }
        float p = p0 + p1;
        p += __shfl_xor(p, 1);
        p += __shfl_xor(p, 2);
        p += __shfl_xor(p, 4);
        p += __shfl_xor(p, 8);
        if (g == 0) sm[OFF_X + f] = p * invT + fc_b[f];
    }
    __syncthreads();

    if (tid < 30) {
        float acc = task_b[tid];
        const float* twp = task_w + tid * 50;
        for (int j = 0; j < 50; ++j) acc = fmaf(sm[OFF_X + j], twp[j], acc);
        out[b * 30 + tid] = acc;
    }
}

extern "C" void kernel_launch(void* const* d_in, const int* in_sizes, int n_in,
                              void* d_out, int out_size, void* d_ws, size_t ws_size,
                              hipStream_t stream) {
    const float* x      = (const float*)d_in[0];
    const float* w1     = (const float*)d_in[1];
    const float* b1     = (const float*)d_in[2];
    const float* w2     = (const float*)d_in[3];
    const float* b2     = (const float*)d_in[4];
    const float* lif_w  = (const float*)d_in[5];
    const float* lif_b  = (const float*)d_in[6];
    const float* fc_w   = (const float*)d_in[7];
    const float* fc_b   = (const float*)d_in[8];
    const float* task_w = (const float*)d_in[9];
    const float* task_b = (const float*)d_in[10];
    const int*   tw     = (const int*)d_in[11];

    int B = in_sizes[0] / 1296;  // x is (B,1,36,36)

    scnn_kernel<<<B, 1024, 0, stream>>>(x, w1, b1, w2, b2, lif_w, lif_b,
                                        fc_w, fc_b, task_w, task_b, tw,
                                        (float*)d_out);
}